// Round 8
// baseline (866.733 us; speedup 1.0000x reference)
//
#include <hip/hip_runtime.h>

// HeteroSAGE on MI355X — round 8: barrier-free wave-private GEMM + fusion.
// R7 post-mortem: 4 blocks/CU made each block 1.6x slower (shared ~1.75TB/s
// wall, all pipes idle) -> latency-bound with too few free-running waves;
// every __syncthreads drains vmcnt(0). Fix: 64-row tiles, each wave stages
// ITS OWN 16 rows (wave-private LDS slice) -> zero barriers anywhere;
// 17KB LDS, launch_bounds(256,6) -> 24 waves/CU. Plus dispatch fusion
// (30 -> 12): multi-job GEMM kernel, fused prep, fused gather_mean,
// ping-pong h_card/h_merch to fuse the per-layer middle 4 GEMMs.

#define N_TX    200000
#define N_CARD  50000
#define N_MERCH 10000
#define NE      200000

typedef __attribute__((ext_vector_type(8))) short short8;
typedef __attribute__((ext_vector_type(4))) short short4v;
typedef __attribute__((ext_vector_type(4))) float f32x4;

__device__ inline unsigned short f2b(float f) {
    unsigned u = __builtin_bit_cast(unsigned, f);
    unsigned r = (u + 0x7fffu + ((u >> 16) & 1u)) >> 16;   // RNE
    return (unsigned short)r;
}
__device__ inline float b2f(unsigned short s) {
    return __builtin_bit_cast(float, (unsigned)s << 16);
}

__device__ __forceinline__ void load_lds16(const void* g, void* l) {
    __builtin_amdgcn_global_load_lds(
        (const __attribute__((address_space(1))) unsigned int*)g,
        (__attribute__((address_space(3))) unsigned int*)l,
        16, 0, 0);
}

// s_waitcnt immediates (gfx9 encoding): vmcnt(0)=0x0f70, lgkmcnt(0)=0xc07f
#define WAIT_VM0()   __builtin_amdgcn_s_waitcnt(0x0f70)
#define WAIT_LGKM0() __builtin_amdgcn_s_waitcnt(0xc07f)

struct GemmJob {
    const unsigned short* A1; const unsigned short* WT1;
    const unsigned short* A2; const unsigned short* WT2;
    const int* rowIdx1; const int* I1; const int* I2;
    const unsigned short* P1; const unsigned short* P2;
    const float* bias; const float* h2W; const float* h2b;
    void* OUT;
    int M; int K; int relu; int blockStart;
};

// 64-row x 128-col tile, 4 waves, wave owns 16 rows. NO barriers.
template <int K>
__device__ __forceinline__ void run_gemm(const GemmJob& j, int bloc, char* smem)
{
    constexpr int RPG = 1024 / (K * 2);     // rows per 1KB group (4 or 8)
    constexpr int GPW = 16 / RPG;           // groups per wave (4 or 2)
    constexpr int GS  = 1040;               // group stride (1KB + 16B pad)
    constexpr int NKK = K / 32;
    constexpr int LSH = (K == 128) ? 4 : 3; // lanes per row shift

    const int tid  = threadIdx.x;
    const int wave = tid >> 6;
    const int lane = tid & 63;
    const int quad = lane >> 4;
    const int l15  = lane & 15;
    const int base = bloc * 64;
    char* ws = smem + wave * 4352;          // wave-private LDS slice
    const int lrow = lane >> LSH;
    const int lcol = (lane & ((1 << LSH) - 1)) * 8;

    f32x4 acc[8];
#pragma unroll
    for (int nt = 0; nt < 8; ++nt) acc[nt] = (f32x4){0.f, 0.f, 0.f, 0.f};

#pragma unroll
    for (int pass = 0; pass < 2; ++pass) {
        const unsigned short* Ag = pass ? j.A2 : j.A1;
        if (!Ag) break;
        const unsigned short* Wg = pass ? j.WT2 : j.WT1;
        const int* rIdx = pass ? nullptr : j.rowIdx1;
        if (pass) WAIT_LGKM0();             // pass-1 ds_reads done before overwrite

        // stage this wave's 16 rows (GPW x 1KB async DMA)
#pragma unroll
        for (int i = 0; i < GPW; ++i) {
            int gr = base + wave * 16 + i * RPG + lrow;
            if (gr >= j.M) gr = j.M - 1;
            int ar = rIdx ? rIdx[gr] : gr;
            load_lds16(Ag + (size_t)ar * K + lcol, ws + i * GS);
        }
        WAIT_VM0();                         // per-wave drain (no barrier)

#pragma unroll
        for (int kk = 0; kk < NKK; ++kk) {
            short8 af = *reinterpret_cast<const short8*>(
                ws + (l15 / RPG) * GS + (l15 % RPG) * (2 * K) + kk * 64 + quad * 16);
#pragma unroll
            for (int nt = 0; nt < 8; ++nt) {
                short8 bf = *reinterpret_cast<const short8*>(
                    Wg + (size_t)(nt * 16 + l15) * K + kk * 32 + quad * 8);
                acc[nt] = __builtin_amdgcn_mfma_f32_16x16x32_bf16(
                    af, bf, acc[nt], 0, 0, 0);
            }
        }
    }

    // epilogue: wave-private LDS transpose in two 8-row sub-rounds
    float* Os = (float*)ws;                 // [8][132] fp32
    float bias_v[8];
#pragma unroll
    for (int nt = 0; nt < 8; ++nt)
        bias_v[nt] = j.bias ? j.bias[nt * 16 + l15] : 0.f;
    const int col4 = (lane & 31) * 4;
    float4 h2w4 = make_float4(0.f, 0.f, 0.f, 0.f);
    if (j.h2W) h2w4 = *reinterpret_cast<const float4*>(j.h2W + col4);
    unsigned short* OUTb = (unsigned short*)j.OUT;
    float* OUTf = (float*)j.OUT;

#pragma unroll
    for (int s = 0; s < 2; ++s) {
        WAIT_LGKM0();                       // prior reads of Os/A done
        if ((quad >> 1) == s) {
            int lr0 = (quad & 1) * 4;       // local row = quad*4+reg - s*8
#pragma unroll
            for (int reg = 0; reg < 4; ++reg)
#pragma unroll
                for (int nt = 0; nt < 8; ++nt)
                    Os[(lr0 + reg) * 132 + nt * 16 + l15] =
                        acc[nt][reg] + bias_v[nt];
        }
        WAIT_LGKM0();                       // writes visible to own wave
#pragma unroll
        for (int rr = 0; rr < 4; ++rr) {
            int lr = rr * 2 + (lane >> 5);
            int gr = base + wave * 16 + s * 8 + lr;
            bool valid = gr < j.M;
            int grc = valid ? gr : 0;
            float4 o = *reinterpret_cast<const float4*>(&Os[lr * 132 + col4]);
            if (j.P1) {
                size_t ix = (size_t)(j.I1 ? j.I1[grc] : grc) * 128 + col4;
                short4v p = *reinterpret_cast<const short4v*>(j.P1 + ix);
                o.x += b2f((unsigned short)p[0]); o.y += b2f((unsigned short)p[1]);
                o.z += b2f((unsigned short)p[2]); o.w += b2f((unsigned short)p[3]);
            }
            if (j.P2) {
                size_t ix = (size_t)(j.I2 ? j.I2[grc] : grc) * 128 + col4;
                short4v p = *reinterpret_cast<const short4v*>(j.P2 + ix);
                o.x += b2f((unsigned short)p[0]); o.y += b2f((unsigned short)p[1]);
                o.z += b2f((unsigned short)p[2]); o.w += b2f((unsigned short)p[3]);
            }
            if (j.relu) {
                o.x = fmaxf(o.x, 0.f); o.y = fmaxf(o.y, 0.f);
                o.z = fmaxf(o.z, 0.f); o.w = fmaxf(o.w, 0.f);
            }
            if (j.h2W) {
                float s2 = o.x * h2w4.x + o.y * h2w4.y + o.z * h2w4.z + o.w * h2w4.w;
                s2 += __shfl_xor(s2, 1);  s2 += __shfl_xor(s2, 2);
                s2 += __shfl_xor(s2, 4);  s2 += __shfl_xor(s2, 8);
                s2 += __shfl_xor(s2, 16);
                if ((lane & 31) == 0 && valid) OUTf[gr] = s2 + j.h2b[0];
            } else if (valid) {
                short4v t;
                t[0] = (short)f2b(o.x); t[1] = (short)f2b(o.y);
                t[2] = (short)f2b(o.z); t[3] = (short)f2b(o.w);
                *reinterpret_cast<short4v*>(OUTb + (size_t)gr * 128 + col4) = t;
            }
        }
    }
}

__global__ __launch_bounds__(256, 6) void mfma_gemm_multi(
    GemmJob j0, GemmJob j1, GemmJob j2, GemmJob j3, int njobs)
{
    __shared__ __align__(16) char smem[4 * 4352];
    GemmJob j = j0;
    if (njobs > 1 && (int)blockIdx.x >= j1.blockStart) j = j1;
    if (njobs > 2 && (int)blockIdx.x >= j2.blockStart) j = j2;
    if (njobs > 3 && (int)blockIdx.x >= j3.blockStart) j = j3;
    int bloc = (int)blockIdx.x - j.blockStart;
    if (j.K == 128) run_gemm<128>(j, bloc, smem);
    else            run_gemm<64>(j, bloc, smem);
}

// ---------------------------------------------------------------------------
// Fused prep: weight transpose/convert (+Wsum/bsum), 3 activation converts,
// edge histogram. Block ranges: [0,1152) weights | [1152,13652) cvt tx |
// [13652,15215) cvt card | [15215,15528) cvt merch | [15528,16310) hist.
__global__ __launch_bounds__(256) void prep_kernel(
    const float* __restrict__ tx_W, const float* __restrict__ card_proj_W,
    const float* __restrict__ merch_proj_W, const float* __restrict__ h1_W,
    const float* __restrict__ conv_Wl, const float* __restrict__ conv_Wr,
    const float* __restrict__ conv_bl,
    unsigned short* __restrict__ WT, float* __restrict__ bsum,
    const float* __restrict__ tx_x, unsigned short* __restrict__ tx_xb,
    const float* __restrict__ card_emb, unsigned short* __restrict__ card_embb,
    const float* __restrict__ merch_emb, unsigned short* __restrict__ merch_embb,
    const int* __restrict__ e_card, const int* __restrict__ e_merch,
    int* __restrict__ hist_c, int* __restrict__ hist_m)
{
    int b = blockIdx.x;
    if (b < 1152) {
        int bx = b & 63, job = b >> 6;
        int K = 128;
        const float* src = nullptr;
        const float* src2 = nullptr;
        if (job == 0) src = tx_W;
        else if (job == 1) { src = card_proj_W; K = 64; }
        else if (job == 2) { src = merch_proj_W; K = 64; }
        else if (job == 3) src = h1_W;
        else {
            int l = (job - 4) / 7, e = (job - 4) % 7;
            const float* Wl = conv_Wl + (size_t)l * 4 * 16384;
            const float* Wr = conv_Wr + (size_t)l * 4 * 16384;
            switch (e) {
                case 0: src = Wl; break;
                case 1: src = Wl + 16384; break;
                case 2: src = Wl + 2 * 16384; break;
                case 3: src = Wl + 3 * 16384; break;
                case 4: src = Wr + 16384; break;
                case 5: src = Wr + 3 * 16384; break;
                default:
                    src = Wr; src2 = Wr + 2 * 16384;
                    if (bx == 0 && threadIdx.x < 128) {
                        const float* bl = conv_bl + (size_t)l * 4 * 128;
                        bsum[l * 128 + threadIdx.x] =
                            bl[threadIdx.x] + bl[2 * 128 + threadIdx.x];
                    }
                    break;
            }
        }
        int e = bx * 256 + threadIdx.x;
        if (e < (K << 7)) {
            int n = (K == 128) ? (e >> 7) : (e >> 6);
            int k = e & (K - 1);
            float v = src[(size_t)k * 128 + n];
            if (src2) v += src2[(size_t)k * 128 + n];
            WT[(size_t)job * 16384 + n * K + k] = f2b(v);
        }
        return;
    }
    if (b < 15528) {
        const float* src; unsigned short* dst; int n; int bb;
        if (b < 13652)      { src = tx_x;      dst = tx_xb;      n = N_TX * 128;    bb = b - 1152; }
        else if (b < 15215) { src = card_emb;  dst = card_embb;  n = N_CARD * 64;   bb = b - 13652; }
        else                { src = merch_emb; dst = merch_embb; n = N_MERCH * 64;  bb = b - 15215; }
        int i = (bb * 256 + threadIdx.x) * 8;
        if (i >= n) return;
        float4 u = *reinterpret_cast<const float4*>(src + i);
        float4 v = *reinterpret_cast<const float4*>(src + i + 4);
        short8 t;
        t[0] = (short)f2b(u.x); t[1] = (short)f2b(u.y);
        t[2] = (short)f2b(u.z); t[3] = (short)f2b(u.w);
        t[4] = (short)f2b(v.x); t[5] = (short)f2b(v.y);
        t[6] = (short)f2b(v.z); t[7] = (short)f2b(v.w);
        *reinterpret_cast<short8*>(dst + i) = t;
        return;
    }
    int i = (b - 15528) * 256 + threadIdx.x;
    if (i < NE) {
        atomicAdd(&hist_c[e_card[i]], 1);
        atomicAdd(&hist_m[e_merch[i]], 1);
    }
}

// ---------------------------------------------------------------------------
__global__ __launch_bounds__(1024) void scan2_kernel(
    const int* __restrict__ hist_c, int* __restrict__ offs_c, int* __restrict__ cur_c, int nc,
    const int* __restrict__ hist_m, int* __restrict__ offs_m, int* __restrict__ cur_m, int nm)
{
    const int* hist = (blockIdx.x == 0) ? hist_c : hist_m;
    int* offs = (blockIdx.x == 0) ? offs_c : offs_m;
    int* cursor = (blockIdx.x == 0) ? cur_c : cur_m;
    int n = (blockIdx.x == 0) ? nc : nm;
    __shared__ int wsum[16];
    __shared__ int s_carry;
    const int tid = threadIdx.x, lane = tid & 63, wid = tid >> 6;
    if (tid == 0) s_carry = 0;
    __syncthreads();
    for (int base = 0; base < n; base += 1024) {
        int i = base + tid;
        int v = (i < n) ? hist[i] : 0;
        int x = v;
#pragma unroll
        for (int d = 1; d < 64; d <<= 1) {
            int t = __shfl_up(x, d);
            if (lane >= d) x += t;
        }
        if (lane == 63) wsum[wid] = x;
        __syncthreads();
        if (wid == 0) {
            int y = (lane < 16) ? wsum[lane] : 0;
#pragma unroll
            for (int d = 1; d < 16; d <<= 1) {
                int t = __shfl_up(y, d);
                if (lane >= d) y += t;
            }
            if (lane < 16) wsum[lane] = y;
        }
        __syncthreads();
        int wbase = (wid > 0) ? wsum[wid - 1] : 0;
        int excl = s_carry + wbase + x - v;
        if (i < n) { offs[i] = excl; cursor[i] = excl; }
        __syncthreads();
        if (tid == 0) s_carry += wsum[15];
        __syncthreads();
    }
    if (threadIdx.x == 0) offs[n] = s_carry;
}

__global__ __launch_bounds__(256) void place_kernel(
    const int* __restrict__ e_card, const int* __restrict__ e_tx_c,
    const int* __restrict__ e_merch, const int* __restrict__ e_tx_m,
    int* __restrict__ cur_c, int* __restrict__ eidx_c,
    int* __restrict__ cur_m, int* __restrict__ eidx_m, int E)
{
    int i = blockIdx.x * 256 + threadIdx.x;
    if (i < E) {
        int pc = atomicAdd(&cur_c[e_card[i]], 1);
        eidx_c[pc] = e_tx_c[i];
        int pm = atomicAdd(&cur_m[e_merch[i]], 1);
        eidx_m[pm] = e_tx_m[i];
    }
}

// fused gather-mean: card segment [0, nb_c) blocks, merch after. 4 dst/block.
__global__ __launch_bounds__(256) void gather_mean2(
    const unsigned short* __restrict__ h_src,
    const int* __restrict__ offs_c, const int* __restrict__ eidx_c,
    unsigned short* __restrict__ out_c, int n_c, int nb_c,
    const int* __restrict__ offs_m, const int* __restrict__ eidx_m,
    unsigned short* __restrict__ out_m, int n_m)
{
    int b = blockIdx.x;
    const int* offs; const int* eidx; unsigned short* out; int nd;
    if (b < nb_c) { offs = offs_c; eidx = eidx_c; out = out_c; nd = n_c; }
    else { b -= nb_c; offs = offs_m; eidx = eidx_m; out = out_m; nd = n_m; }
    const int lane = threadIdx.x & 63;
    const int d = b * 4 + (threadIdx.x >> 6);
    if (d >= nd) return;
    const int s = offs[d], e = offs[d + 1];
    float a0 = 0.f, a1 = 0.f;
    for (int p = s; p < e; ++p) {
        int tx = eidx[p];
        unsigned v = *reinterpret_cast<const unsigned*>(
            h_src + (size_t)tx * 128 + lane * 2);
        a0 += b2f((unsigned short)(v & 0xffff));
        a1 += b2f((unsigned short)(v >> 16));
    }
    const float inv = (e > s) ? 1.0f / (float)(e - s) : 0.f;
    unsigned o = ((unsigned)f2b(a1 * inv) << 16) | f2b(a0 * inv);
    *reinterpret_cast<unsigned*>(out + (size_t)d * 128 + lane * 2) = o;
}

// ---------------------------------------------------------------------------
extern "C" void kernel_launch(void* const* d_in, const int* in_sizes, int n_in,
                              void* d_out, int out_size, void* d_ws, size_t ws_size,
                              hipStream_t stream)
{
    const float* tx_x        = (const float*)d_in[0];
    const int*   card_ids    = (const int*)d_in[1];
    const int*   merch_ids   = (const int*)d_in[2];
    const int*   e_card      = (const int*)d_in[3];
    const int*   e_tx_c      = (const int*)d_in[4];
    const int*   e_merch     = (const int*)d_in[5];
    const int*   e_tx_m      = (const int*)d_in[6];
    const float* card_emb    = (const float*)d_in[7];
    const float* merch_emb   = (const float*)d_in[8];
    const float* card_proj_W = (const float*)d_in[9];
    const float* card_proj_b = (const float*)d_in[10];
    const float* merch_proj_W= (const float*)d_in[11];
    const float* merch_proj_b= (const float*)d_in[12];
    const float* tx_W        = (const float*)d_in[13];
    const float* tx_b        = (const float*)d_in[14];
    const float* conv_Wl     = (const float*)d_in[15];
    const float* conv_bl     = (const float*)d_in[16];
    const float* conv_Wr     = (const float*)d_in[17];
    const float* h1_W        = (const float*)d_in[18];
    const float* h1_b        = (const float*)d_in[19];
    const float* h2_W        = (const float*)d_in[20];
    const float* h2_b        = (const float*)d_in[21];

    char* wsb = (char*)d_ws;
    auto alloc = [&](size_t bytes) {
        char* p = wsb; wsb += (bytes + 255) & ~(size_t)255; return p;
    };
    unsigned short* tx_xb      = (unsigned short*)alloc((size_t)N_TX * 128 * 2);
    unsigned short* card_embb  = (unsigned short*)alloc((size_t)N_CARD * 64 * 2);
    unsigned short* merch_embb = (unsigned short*)alloc((size_t)N_MERCH * 64 * 2);
    unsigned short* h_tx       = (unsigned short*)alloc((size_t)N_TX * 128 * 2);
    unsigned short* h_card_a   = (unsigned short*)alloc((size_t)N_CARD * 128 * 2);
    unsigned short* h_card_b   = (unsigned short*)alloc((size_t)N_CARD * 128 * 2);
    unsigned short* h_merch_a  = (unsigned short*)alloc((size_t)N_MERCH * 128 * 2);
    unsigned short* h_merch_b  = (unsigned short*)alloc((size_t)N_MERCH * 128 * 2);
    unsigned short* p_card     = (unsigned short*)alloc((size_t)N_CARD * 128 * 2);
    unsigned short* p_merch    = (unsigned short*)alloc((size_t)N_MERCH * 128 * 2);
    unsigned short* mean_card  = (unsigned short*)alloc((size_t)N_CARD * 128 * 2);
    unsigned short* mean_merch = (unsigned short*)alloc((size_t)N_MERCH * 128 * 2);
    unsigned short* WT         = (unsigned short*)alloc((size_t)18 * 16384 * 2);
    float* bsum = (float*)alloc(2 * 128 * 4);
    int* hist_c = (int*)alloc((size_t)(N_CARD + N_MERCH) * 4);  // one memset
    int* hist_m = hist_c + N_CARD;
    int* offs_c = (int*)alloc((size_t)(N_CARD + 1) * 4);
    int* cur_c  = (int*)alloc((size_t)N_CARD * 4);
    int* eidx_c = (int*)alloc((size_t)NE * 4);
    int* offs_m = (int*)alloc((size_t)(N_MERCH + 1) * 4);
    int* cur_m  = (int*)alloc((size_t)N_MERCH * 4);
    int* eidx_m = (int*)alloc((size_t)NE * 4);

    auto WTj = [&](int job) { return WT + (size_t)job * 16384; };

    GemmJob Z = {};   // zeroed template
    auto mkjob = [&](const unsigned short* A1, const unsigned short* W1,
                     const unsigned short* A2, const unsigned short* W2,
                     const int* ri, const float* bias,
                     const unsigned short* P1, const int* I1,
                     const unsigned short* P2, const int* I2,
                     const float* h2w, const float* h2bb, void* out,
                     int M, int K, int relu, int start) {
        GemmJob g = Z;
        g.A1 = A1; g.WT1 = W1; g.A2 = A2; g.WT2 = W2; g.rowIdx1 = ri;
        g.bias = bias; g.P1 = P1; g.I1 = I1; g.P2 = P2; g.I2 = I2;
        g.h2W = h2w; g.h2b = h2bb; g.OUT = out;
        g.M = M; g.K = K; g.relu = relu; g.blockStart = start;
        return g;
    };
    auto nb = [](int M) { return (M + 63) / 64; };   // 64-row tiles

    // D0: memset + fused prep (weights, converts, hist)
    hipMemsetAsync(hist_c, 0, (size_t)(N_CARD + N_MERCH) * 4, stream);
    prep_kernel<<<dim3(16310), dim3(256), 0, stream>>>(
        tx_W, card_proj_W, merch_proj_W, h1_W, conv_Wl, conv_Wr, conv_bl,
        WT, bsum, tx_x, tx_xb, card_emb, card_embb, merch_emb, merch_embb,
        e_card, e_merch, hist_c, hist_m);
    // D1/D2: CSR
    scan2_kernel<<<dim3(2), dim3(1024), 0, stream>>>(
        hist_c, offs_c, cur_c, N_CARD, hist_m, offs_m, cur_m, N_MERCH);
    place_kernel<<<dim3((NE + 255) / 256), dim3(256), 0, stream>>>(
        e_card, e_tx_c, e_merch, e_tx_m, cur_c, eidx_c, cur_m, eidx_m, NE);

    // D3: fused encoders (tx, card, merch)
    {
        GemmJob a = mkjob(tx_xb, WTj(0), nullptr, nullptr, nullptr, tx_b,
                          nullptr, nullptr, nullptr, nullptr, nullptr, nullptr,
                          h_tx, N_TX, 128, 1, 0);
        GemmJob b = mkjob(card_embb, WTj(1), nullptr, nullptr, card_ids,
                          card_proj_b, nullptr, nullptr, nullptr, nullptr,
                          nullptr, nullptr, h_card_a, N_CARD, 64, 0, nb(N_TX));
        GemmJob c = mkjob(merch_embb, WTj(2), nullptr, nullptr, merch_ids,
                          merch_proj_b, nullptr, nullptr, nullptr, nullptr,
                          nullptr, nullptr, h_merch_a, N_MERCH, 64, 0,
                          nb(N_TX) + nb(N_CARD));
        int grid = nb(N_TX) + nb(N_CARD) + nb(N_MERCH);
        mfma_gemm_multi<<<dim3(grid), dim3(256), 0, stream>>>(a, b, c, c, 3);
    }

    const unsigned short* hc = h_card_a;  unsigned short* hc_n = h_card_b;
    const unsigned short* hm = h_merch_a; unsigned short* hm_n = h_merch_b;

    for (int l = 0; l < 2; ++l) {
        const float* bl = conv_bl + (size_t)l * 4 * 128;
        int j = 4 + l * 7;   // Wl0,Wl1,Wl2,Wl3,Wr1,Wr3,Wsum

        // D4: fused gather-mean (card + merch)
        gather_mean2<<<dim3((N_CARD + 3) / 4 + (N_MERCH + 3) / 4),
                       dim3(256), 0, stream>>>(
            h_tx, offs_c, eidx_c, mean_card, N_CARD, (N_CARD + 3) / 4,
            offs_m, eidx_m, mean_merch, N_MERCH);

        // D5: fused middle — p_card, p_merch, card-upd, merch-upd (ping-pong)
        {
            int s0 = 0, s1 = nb(N_CARD), s2 = s1 + nb(N_MERCH),
                s3 = s2 + nb(N_CARD);
            GemmJob a = mkjob(hc, WTj(j + 0), nullptr, nullptr, nullptr, nullptr,
                              nullptr, nullptr, nullptr, nullptr, nullptr, nullptr,
                              p_card, N_CARD, 128, 0, s0);
            GemmJob b = mkjob(hm, WTj(j + 2), nullptr, nullptr, nullptr, nullptr,
                              nullptr, nullptr, nullptr, nullptr, nullptr, nullptr,
                              p_merch, N_MERCH, 128, 0, s1);
            GemmJob c = mkjob(mean_card, WTj(j + 1), hc, WTj(j + 4), nullptr,
                              bl + 1 * 128, nullptr, nullptr, nullptr, nullptr,
                              nullptr, nullptr, hc_n, N_CARD, 128, 1, s2);
            GemmJob d = mkjob(mean_merch, WTj(j + 3), hm, WTj(j + 5), nullptr,
                              bl + 3 * 128, nullptr, nullptr, nullptr, nullptr,
                              nullptr, nullptr, hm_n, N_MERCH, 128, 1, s3);
            int grid = s3 + nb(N_MERCH);
            mfma_gemm_multi<<<dim3(grid), dim3(256), 0, stream>>>(a, b, c, d, 4);
        }

        // D6: tx update (in-place row-local; M divisible by 64 so no clamp race)
        {
            GemmJob a = mkjob(h_tx, WTj(j + 6), nullptr, nullptr, nullptr,
                              bsum + l * 128, p_card, e_card, p_merch, e_merch,
                              nullptr, nullptr, h_tx, N_TX, 128, 1, 0);
            mfma_gemm_multi<<<dim3(nb(N_TX)), dim3(256), 0, stream>>>(
                a, a, a, a, 1);
        }

        // ping-pong
        const unsigned short* t1 = hc; hc = hc_n; hc_n = (unsigned short*)t1;
        const unsigned short* t2 = hm; hm = hm_n; hm_n = (unsigned short*)t2;
    }

    // D10: head — logits = relu(h_tx @ h1_W + h1_b) . h2_W + h2_b  (fp32 out)
    {
        GemmJob a = mkjob(h_tx, WTj(3), nullptr, nullptr, nullptr, h1_b,
                          nullptr, nullptr, nullptr, nullptr, h2_W, h2_b,
                          d_out, N_TX, 128, 1, 0);
        mfma_gemm_multi<<<dim3(nb(N_TX)), dim3(256), 0, stream>>>(a, a, a, a, 1);
    }
}